// Round 4
// baseline (635.468 us; speedup 1.0000x reference)
//
#include <hip/hip_runtime.h>
#include <math.h>

#define B_ 128
#define N_ 2048
#define D_ 256
#define NHEADS 32   // 2 head-sets * 16 heads

// ws layout (float offsets)
#define POOLED_OFF 0              // 32768
#define PHI_OFF    32768          // B*32*256 ushort = 524288 fl
#define PLO_OFF    557056         // 524288 fl
#define ML_OFF     1081344        // B*32*4*2 = 32768
#define FEATP_OFF  1114112        // 4*B*256*32 = 4194304 (d-major)

// LDS byte offsets for k_attn (total 42752 B)
#define XT_S    0        // [256 d][72 shorts] = 36864 B (stride 144)
#define ATT_S   36864    // [32 h][72 shorts]  = 4608 B  (stride 144)
#define SMAX_S  41472    // [4 w][32 h] f32
#define SSUM_S  41984    // [4 w][32 h] f32
#define ALPHA_S 42496    // [32] f32
#define MNEW_S  42624    // [32] f32
#define LDS_TOT 42752

typedef __attribute__((ext_vector_type(8))) short short8;
typedef __attribute__((ext_vector_type(4))) float f32x4;

__device__ __forceinline__ unsigned perm(unsigned a, unsigned b, unsigned s) {
    return __builtin_amdgcn_perm(a, b, s);
}
__device__ __forceinline__ void atomic_max_f32(float* addr, float v) {
    if (v >= 0.0f) atomicMax((int*)addr, __float_as_int(v + 0.0f));
    else           atomicMin((unsigned int*)addr, __float_as_uint(v));
}
__device__ __forceinline__ unsigned short f2bf(float f) {   // RNE
    unsigned u = __float_as_uint(f);
    u += 0x7fff + ((u >> 16) & 1);
    return (unsigned short)(u >> 16);
}
__device__ __forceinline__ float bf2f(unsigned short h) {
    return __uint_as_float(((unsigned)h) << 16);
}
__device__ __forceinline__ unsigned pack2bf(float a, float b) {
    return (unsigned)f2bf(a) | ((unsigned)f2bf(b) << 16);
}
__device__ __forceinline__ short8 make_s8(unsigned a, unsigned b, unsigned c, unsigned d) {
    union { unsigned u[4]; short8 s; } x;
    x.u[0] = a; x.u[1] = b; x.u[2] = c; x.u[3] = d;
    return x.s;
}
// fp32x8 -> bf16 hi (truncate) + lo (residual, truncate). hi+lo reconstructs to ~2^-16.
__device__ __forceinline__ void cvt_hilo(const float4& f0, const float4& f1,
                                         short8& hi, short8& lo) {
    unsigned u0 = __float_as_uint(f0.x), u1 = __float_as_uint(f0.y);
    unsigned u2 = __float_as_uint(f0.z), u3 = __float_as_uint(f0.w);
    unsigned u4 = __float_as_uint(f1.x), u5 = __float_as_uint(f1.y);
    unsigned u6 = __float_as_uint(f1.z), u7 = __float_as_uint(f1.w);
    hi = make_s8(perm(u1, u0, 0x07060302u), perm(u3, u2, 0x07060302u),
                 perm(u5, u4, 0x07060302u), perm(u7, u6, 0x07060302u));
    unsigned r0 = __float_as_uint(f0.x - __uint_as_float(u0 & 0xffff0000u));
    unsigned r1 = __float_as_uint(f0.y - __uint_as_float(u1 & 0xffff0000u));
    unsigned r2 = __float_as_uint(f0.z - __uint_as_float(u2 & 0xffff0000u));
    unsigned r3 = __float_as_uint(f0.w - __uint_as_float(u3 & 0xffff0000u));
    unsigned r4 = __float_as_uint(f1.x - __uint_as_float(u4 & 0xffff0000u));
    unsigned r5 = __float_as_uint(f1.y - __uint_as_float(u5 & 0xffff0000u));
    unsigned r6 = __float_as_uint(f1.z - __uint_as_float(u6 & 0xffff0000u));
    unsigned r7 = __float_as_uint(f1.w - __uint_as_float(u7 & 0xffff0000u));
    lo = make_s8(perm(r1, r0, 0x07060302u), perm(r3, r2, 0x07060302u),
                 perm(r5, r4, 0x07060302u), perm(r7, r6, 0x07060302u));
}
// fp32x8 -> bf16 (round half up) packed as 4 dwords
__device__ __forceinline__ void packrow(const float4& a, const float4& b, unsigned w[4]) {
    unsigned u0 = __float_as_uint(a.x) + 0x8000u, u1 = __float_as_uint(a.y) + 0x8000u;
    unsigned u2 = __float_as_uint(a.z) + 0x8000u, u3 = __float_as_uint(a.w) + 0x8000u;
    unsigned u4 = __float_as_uint(b.x) + 0x8000u, u5 = __float_as_uint(b.y) + 0x8000u;
    unsigned u6 = __float_as_uint(b.z) + 0x8000u, u7 = __float_as_uint(b.w) + 0x8000u;
    w[0] = perm(u1, u0, 0x07060302u); w[1] = perm(u3, u2, 0x07060302u);
    w[2] = perm(u5, u4, 0x07060302u); w[3] = perm(u7, u6, 0x07060302u);
}

__global__ __launch_bounds__(256) void k_init(float* __restrict__ pooled) {
    pooled[blockIdx.x * 256 + threadIdx.x] = -INFINITY;
}

// global max-pool only (no x conversion). grid B*16; block covers 128 rows.
__global__ __launch_bounds__(256) void k_pool(const float* __restrict__ inp,
                                              float* __restrict__ pooled) {
    int b = blockIdx.x >> 4;
    int ch = blockIdx.x & 15;
    int t = threadIdx.x;
    int sub = t >> 6;
    int dq = (t & 63) * 4;
    const float* p = inp + ((size_t)(b * N_ + ch * 128 + sub)) * D_ + dq;
    float4 m = {-INFINITY, -INFINITY, -INFINITY, -INFINITY};
#pragma unroll 8
    for (int i = 0; i < 32; ++i) {
        float4 v = *(const float4*)(p + (size_t)i * 4 * D_);
        m.x = fmaxf(m.x, v.x); m.y = fmaxf(m.y, v.y);
        m.z = fmaxf(m.z, v.z); m.w = fmaxf(m.w, v.w);
    }
    __shared__ float sm[4 * 256];
    sm[sub * 256 + dq + 0] = m.x;
    sm[sub * 256 + dq + 1] = m.y;
    sm[sub * 256 + dq + 2] = m.z;
    sm[sub * 256 + dq + 3] = m.w;
    __syncthreads();
    float v = fmaxf(fmaxf(sm[t], sm[256 + t]), fmaxf(sm[512 + t], sm[768 + t]));
    atomic_max_f32(pooled + b * D_ + t, v);
}

// q = pooled @ Wq^T (both sets), P = q @ Wk -> bf16 hi/lo
__global__ __launch_bounds__(256) void k_qp(const float* __restrict__ pooled,
                                            const float* __restrict__ Wq0,
                                            const float* __restrict__ Wq1,
                                            const float* __restrict__ Wk,
                                            unsigned short* __restrict__ Phi,
                                            unsigned short* __restrict__ Plo) {
    __shared__ float pl[D_];
    __shared__ float ql[1024];
    int b = blockIdx.x, t = threadIdx.x;
    pl[t] = pooled[b * D_ + t];
    __syncthreads();
    for (int rep = 0; rep < 4; ++rep) {
        int idx = rep * 256 + t;
        const float* Wq = (idx < 512) ? Wq0 : Wq1;
        int row = idx & 511;
        const float4* wr = (const float4*)(Wq + (size_t)row * D_);
        float acc = 0.0f;
        for (int dqi = 0; dqi < 64; ++dqi) {
            float4 w = wr[dqi];
            const float* pp = &pl[dqi * 4];
            acc += w.x * pp[0] + w.y * pp[1] + w.z * pp[2] + w.w * pp[3];
        }
        ql[idx] = acc;
    }
    __syncthreads();
    float wk[32];
#pragma unroll
    for (int k = 0; k < 32; ++k) wk[k] = Wk[k * D_ + t];
    for (int j = 0; j < NHEADS; ++j) {
        const float* q = &ql[(j >> 4) * 512 + (j & 15) * 32];
        float acc = 0.0f;
#pragma unroll
        for (int k = 0; k < 32; ++k) acc = fmaf(q[k], wk[k], acc);
        unsigned short hi = f2bf(acc);
        unsigned short lo = f2bf(acc - bf2f(hi));
        Phi[((size_t)b * NHEADS + j) * D_ + t] = hi;
        Plo[((size_t)b * NHEADS + j) * D_ + t] = lo;
    }
}

// Fused flash-style attention: single fp32 read of x.
// grid = B*4 (b, ns); block 256 = 4 waves; per block: 512 nodes in 8 chunks of 64.
__global__ __launch_bounds__(256) void k_attn(const float* __restrict__ inp,
                                              const unsigned short* __restrict__ Phi,
                                              const unsigned short* __restrict__ Plo,
                                              float* __restrict__ ml,
                                              float* __restrict__ featp) {
    __shared__ uint4 smem4[LDS_TOT / 16];
    char* smem = (char*)smem4;
    float* smax   = (float*)(smem + SMAX_S);
    float* ssum   = (float*)(smem + SSUM_S);
    float* alphas = (float*)(smem + ALPHA_S);
    float* mnews  = (float*)(smem + MNEW_S);

    int b = blockIdx.x >> 2, ns = blockIdx.x & 3;
    int t = threadIdx.x;
    int w = t >> 6, lane = t & 63, lq = lane >> 4, lm = lane & 15;
    size_t gnode0 = (size_t)b * N_ + ns * 512;

    float Mrun = -INFINITY, lrun = 0.0f;       // meaningful on t<32
    f32x4 acc_o[2][4];
#pragma unroll
    for (int ht = 0; ht < 2; ++ht)
#pragma unroll
        for (int dt = 0; dt < 4; ++dt) acc_o[ht][dt] = (f32x4){0.f, 0.f, 0.f, 0.f};

    for (int cc = 0; cc < 8; ++cc) {
        __syncthreads();   // B1: prev chunk's O-MFMA done reading XT/ATT
        // ---- xT build: re-read chunk fp32 (L2-hot), transpose to [d][n] bf16 ----
#pragma unroll
        for (int rep = 0; rep < 2; ++rep) {
            int id = t + 256 * rep;
            int sn = id & 15, sd = id >> 4;            // n0 = sn*4, d0 = sd*8
            const float* gp = inp + (gnode0 + cc * 64 + sn * 4) * (size_t)D_ + sd * 8;
            unsigned w0[4], w1[4], w2[4], w3[4];
            {
                float4 a = *(const float4*)(gp), bq = *(const float4*)(gp + 4);
                packrow(a, bq, w0);
            }
            {
                float4 a = *(const float4*)(gp + D_), bq = *(const float4*)(gp + D_ + 4);
                packrow(a, bq, w1);
            }
            {
                float4 a = *(const float4*)(gp + 2 * D_), bq = *(const float4*)(gp + 2 * D_ + 4);
                packrow(a, bq, w2);
            }
            {
                float4 a = *(const float4*)(gp + 3 * D_), bq = *(const float4*)(gp + 3 * D_ + 4);
                packrow(a, bq, w3);
            }
            uint2 T[8];
#pragma unroll
            for (int c2 = 0; c2 < 4; ++c2) {
                T[2 * c2 + 0].x = perm(w1[c2], w0[c2], 0x05040100u);
                T[2 * c2 + 0].y = perm(w3[c2], w2[c2], 0x05040100u);
                T[2 * c2 + 1].x = perm(w1[c2], w0[c2], 0x07060302u);
                T[2 * c2 + 1].y = perm(w3[c2], w2[c2], 0x07060302u);
            }
#pragma unroll
            for (int j = 0; j < 8; ++j) {
                int jj = (j + sd) & 7;
                *(uint2*)(smem + XT_S + (size_t)(sd * 8 + jj) * 144 + sn * 8) = T[jj];
            }
        }
        // ---- S^T for wave's 16 nodes x 32 heads, K=256 (fp32->hi/lo in reg) ----
        f32x4 acc_s[2];
        acc_s[0] = (f32x4){0.f, 0.f, 0.f, 0.f};
        acc_s[1] = (f32x4){0.f, 0.f, 0.f, 0.f};
        const float* xr = inp + (gnode0 + cc * 64 + w * 16 + lm) * (size_t)D_ + lq * 8;
#pragma unroll
        for (int dc = 0; dc < 8; ++dc) {
            float4 f0 = *(const float4*)(xr + dc * 32);
            float4 f1 = *(const float4*)(xr + dc * 32 + 4);
            short8 ah, al;
            cvt_hilo(f0, f1, ah, al);
#pragma unroll
            for (int ht = 0; ht < 2; ++ht) {
                size_t poff = ((size_t)b * NHEADS + ht * 16 + lm) * D_ + dc * 32 + lq * 8;
                short8 bh = *(const short8*)(Phi + poff);
                short8 bl = *(const short8*)(Plo + poff);
                acc_s[ht] = __builtin_amdgcn_mfma_f32_16x16x32_bf16(ah, bh, acc_s[ht], 0, 0, 0);
                acc_s[ht] = __builtin_amdgcn_mfma_f32_16x16x32_bf16(ah, bl, acc_s[ht], 0, 0, 0);
                acc_s[ht] = __builtin_amdgcn_mfma_f32_16x16x32_bf16(al, bh, acc_s[ht], 0, 0, 0);
            }
        }
        // ---- chunk column-max (per head) ----
        float m0 = fmaxf(fmaxf(acc_s[0][0], acc_s[0][1]), fmaxf(acc_s[0][2], acc_s[0][3]));
        float m1 = fmaxf(fmaxf(acc_s[1][0], acc_s[1][1]), fmaxf(acc_s[1][2], acc_s[1][3]));
        m0 = fmaxf(m0, __shfl_xor(m0, 16)); m0 = fmaxf(m0, __shfl_xor(m0, 32));
        m1 = fmaxf(m1, __shfl_xor(m1, 16)); m1 = fmaxf(m1, __shfl_xor(m1, 32));
        if (lane < 32) smax[w * 32 + lane] = (lane < 16) ? m0 : m1;
        __syncthreads();   // B2: smax + XT ready
        float alpha_r = 0.0f;
        if (t < 32) {
            float mc = fmaxf(fmaxf(smax[t], smax[32 + t]), fmaxf(smax[64 + t], smax[96 + t]));
            float Mn = fmaxf(Mrun, mc);
            alpha_r = __expf(Mrun - Mn);
            Mrun = Mn;
            alphas[t] = alpha_r;
            mnews[t] = Mn;
        }
        __syncthreads();   // B3: alpha/mnew ready
        float Mn0 = mnews[lm], Mn1 = mnews[16 + lm];
        {
            float e0 = __expf(acc_s[0][0] - Mn0), e1 = __expf(acc_s[0][1] - Mn0);
            float e2 = __expf(acc_s[0][2] - Mn0), e3 = __expf(acc_s[0][3] - Mn0);
            float s0 = (e0 + e1) + (e2 + e3);
            uint2 pk; pk.x = pack2bf(e0, e1); pk.y = pack2bf(e2, e3);
            *(uint2*)(smem + ATT_S + (size_t)lm * 144 + (w * 16 + lq * 4) * 2) = pk;
            float f0 = __expf(acc_s[1][0] - Mn1), f1 = __expf(acc_s[1][1] - Mn1);
            float f2 = __expf(acc_s[1][2] - Mn1), f3 = __expf(acc_s[1][3] - Mn1);
            float s1 = (f0 + f1) + (f2 + f3);
            pk.x = pack2bf(f0, f1); pk.y = pack2bf(f2, f3);
            *(uint2*)(smem + ATT_S + (size_t)(16 + lm) * 144 + (w * 16 + lq * 4) * 2) = pk;
            s0 += __shfl_xor(s0, 16); s0 += __shfl_xor(s0, 32);
            s1 += __shfl_xor(s1, 16); s1 += __shfl_xor(s1, 32);
            if (lane < 32) ssum[w * 32 + lane] = (lane < 16) ? s0 : s1;
        }
        // rescale acc_o rows by alpha[h]
        float4 al0 = *(const float4*)(alphas + lq * 4);
        float4 al1 = *(const float4*)(alphas + 16 + lq * 4);
#pragma unroll
        for (int dt = 0; dt < 4; ++dt) {
            acc_o[0][dt][0] *= al0.x; acc_o[0][dt][1] *= al0.y;
            acc_o[0][dt][2] *= al0.z; acc_o[0][dt][3] *= al0.w;
            acc_o[1][dt][0] *= al1.x; acc_o[1][dt][1] *= al1.y;
            acc_o[1][dt][2] *= al1.z; acc_o[1][dt][3] *= al1.w;
        }
        __syncthreads();   // B4: att + ssum ready
        if (t < 32) {
            float s4 = ssum[t] + ssum[32 + t] + ssum[64 + t] + ssum[96 + t];
            lrun = lrun * alpha_r + s4;
        }
        // ---- O += att(32h x 64n) * x(64n x 256d), wave owns 64 d ----
#pragma unroll
        for (int ks = 0; ks < 2; ++ks) {
            short8 a0 = *(const short8*)(smem + ATT_S + (size_t)lm * 144 + ks * 64 + lq * 16);
            short8 a1 = *(const short8*)(smem + ATT_S + (size_t)(16 + lm) * 144 + ks * 64 + lq * 16);
#pragma unroll
            for (int dt = 0; dt < 4; ++dt) {
                short8 bf = *(const short8*)(smem + XT_S +
                             (size_t)(w * 64 + dt * 16 + lm) * 144 + ks * 64 + lq * 16);
                acc_o[0][dt] = __builtin_amdgcn_mfma_f32_16x16x32_bf16(a0, bf, acc_o[0][dt], 0, 0, 0);
                acc_o[1][dt] = __builtin_amdgcn_mfma_f32_16x16x32_bf16(a1, bf, acc_o[1][dt], 0, 0, 0);
            }
        }
    }
    // ---- epilogue: featp [ns][b][d][h], ml (block max, sum) ----
    float* fb = featp + (size_t)(ns * B_ + b) * D_ * NHEADS;
#pragma unroll
    for (int ht = 0; ht < 2; ++ht)
#pragma unroll
        for (int dt = 0; dt < 4; ++dt) {
            int d = w * 64 + dt * 16 + lm;
            int h0 = ht * 16 + lq * 4;
            *(f32x4*)(fb + (size_t)d * NHEADS + h0) = acc_o[ht][dt];
        }
    if (t < 32) {
        float* mlp = ml + (((size_t)b * NHEADS + t) * 4 + ns) * 2;
        mlp[0] = Mrun;
        mlp[1] = lrun;
    }
}

// epilogue: merge chunk partials, feat@We^T, dx, dx@Wout^T + bias, leaky
__global__ __launch_bounds__(256) void k_out(const float* __restrict__ featp,
                                             const float* __restrict__ ml,
                                             const float* __restrict__ We,
                                             const float* __restrict__ Wout,
                                             const float* __restrict__ bout,
                                             float* __restrict__ out) {
    __shared__ float f[NHEADS * 257];
    __shared__ float bhrs[512];
    __shared__ float dxs[256];
    __shared__ float wns[4 * 32];
    __shared__ float linv2[32];
    int b = blockIdx.x, t = threadIdx.x;
    if (t < 32) {
        const float* mlb = ml + ((size_t)b * NHEADS + t) * 8;
        float M = fmaxf(fmaxf(mlb[0], mlb[2]), fmaxf(mlb[4], mlb[6]));
        float e0 = __expf(mlb[0] - M), e1 = __expf(mlb[2] - M);
        float e2 = __expf(mlb[4] - M), e3 = __expf(mlb[6] - M);
        float L = e0 * mlb[1] + e1 * mlb[3] + e2 * mlb[5] + e3 * mlb[7];
        wns[0 * 32 + t] = e0; wns[1 * 32 + t] = e1;
        wns[2 * 32 + t] = e2; wns[3 * 32 + t] = e3;
        linv2[t] = 1.0f / L;
    }
    __syncthreads();
    float fj[32];
#pragma unroll
    for (int j = 0; j < 32; ++j) fj[j] = 0.0f;
#pragma unroll
    for (int ns = 0; ns < 4; ++ns) {
        const float* fp = featp + ((size_t)(ns * B_ + b) * D_ + t) * NHEADS;
#pragma unroll
        for (int j4 = 0; j4 < 8; ++j4) {
            float4 v = *(const float4*)(fp + j4 * 4);
            fj[j4 * 4 + 0] += wns[ns * 32 + j4 * 4 + 0] * v.x;
            fj[j4 * 4 + 1] += wns[ns * 32 + j4 * 4 + 1] * v.y;
            fj[j4 * 4 + 2] += wns[ns * 32 + j4 * 4 + 2] * v.z;
            fj[j4 * 4 + 3] += wns[ns * 32 + j4 * 4 + 3] * v.w;
        }
    }
#pragma unroll
    for (int j = 0; j < 32; ++j) f[j * 257 + t] = fj[j] * linv2[j];
    __syncthreads();
    for (int rep = 0; rep < 2; ++rep) {
        int idx = rep * 256 + t;
        int j = idx >> 4, r = idx & 15;
        const float* wrow = We + (size_t)r * D_;
        const float* ff = &f[j * 257];
        float acc = 0.0f;
        for (int d = 0; d < D_; ++d) acc = fmaf(ff[d], wrow[d], acc);
        bhrs[idx] = acc;
    }
    __syncthreads();
    {
        int h = t >> 4, r = t & 15;
        dxs[t] = bhrs[h * 16 + r] - bhrs[(16 + h) * 16 + r];
    }
    __syncthreads();
    float acc = bout[t];
    const float* wrow = Wout + (size_t)t * 256;
    for (int c = 0; c < 256; ++c) acc = fmaf(dxs[c], wrow[c], acc);
    out[(size_t)b * D_ + t] = acc >= 0.0f ? acc : 0.01f * acc;
}

extern "C" void kernel_launch(void* const* d_in, const int* in_sizes, int n_in,
                              void* d_out, int out_size, void* d_ws, size_t ws_size,
                              hipStream_t stream) {
    const float* inp  = (const float*)d_in[0];
    // d_in[1] = batch_ids (equal-size contiguous graphs)
    const float* Wk   = (const float*)d_in[2];
    const float* Wq0  = (const float*)d_in[3];
    const float* Wq1  = (const float*)d_in[4];
    const float* We   = (const float*)d_in[5];
    const float* Wout = (const float*)d_in[6];
    const float* bout = (const float*)d_in[7];
    float* out = (float*)d_out;
    float* ws  = (float*)d_ws;
    float* pooled = ws + POOLED_OFF;
    unsigned short* Phi = (unsigned short*)(ws + PHI_OFF);
    unsigned short* Plo = (unsigned short*)(ws + PLO_OFF);
    float* ml     = ws + ML_OFF;
    float* featp  = ws + FEATP_OFF;

    k_init<<<dim3(128), dim3(256), 0, stream>>>(pooled);
    k_pool<<<dim3(2048), dim3(256), 0, stream>>>(inp, pooled);
    k_qp<<<dim3(128), dim3(256), 0, stream>>>(pooled, Wq0, Wq1, Wk, Phi, Plo);
    k_attn<<<dim3(512), dim3(256), 0, stream>>>(inp, Phi, Plo, ml, featp);
    k_out<<<dim3(128), dim3(256), 0, stream>>>(featp, ml, We, Wout, bout, out);
}